// Round 1
// baseline (731.427 us; speedup 1.0000x reference)
//
#include <hip/hip_runtime.h>
#include <hip/hip_bf16.h>
#include <stdint.h>

// ---------------------------------------------------------------------------
// LeViT attention block, fused:
//  k_cvt      : fp32 -> bf16 for x, qkv_w, proj_w
//  k_bnfold   : fold BN into per-channel A,B  (y = x*A + B)
//  k_biasexp  : expand attn_biases[h, bias_idxs[q,k]] -> [12][256][256] fp32
//  k_attn     : per (b,head): qkv GEMM (K=768) + BN + QK^T + bias + softmax
//               + PV + hardswish -> attnout bf16 [16384][3072]
//  k_proj     : proj GEMM (K=3072) + BN -> d_out fp32 [16384][768]
// MFMA 16x16x32 bf16. C/D layout: col=lane&15, row=(lane>>4)*4+reg (m89).
// A/B frag: 8 contiguous k at k=(lane>>4)*8+j  -> one ds_read_b128 per frag.
// All LDS tiles XOR-swizzled: byte ^= (row&7)<<4  (16B-granular, both sides).
// ---------------------------------------------------------------------------

typedef __attribute__((ext_vector_type(8))) __bf16 bf16x8;
typedef __attribute__((ext_vector_type(4))) float  f32x4;

#define HEADS  12
#define EPS_   1e-5f
#define SCALE_ 0.125f   // KEY_DIM^-0.5 = 64^-0.5

__device__ __forceinline__ unsigned short f2bf(float x) {
  __hip_bfloat16 h = __float2bfloat16(x);
  return *reinterpret_cast<unsigned short*>(&h);
}

__device__ __forceinline__ f32x4 mfma16(bf16x8 a, bf16x8 b, f32x4 c) {
  return __builtin_amdgcn_mfma_f32_16x16x32_bf16(a, b, c, 0, 0, 0);
}

#define SWZ(byte, row) ((byte) ^ (((row) & 7) << 4))

// ---------------------------------------------------------------------------
__global__ void k_cvt(const float* __restrict__ in, unsigned short* __restrict__ out, int n4) {
  int i = blockIdx.x * blockDim.x + threadIdx.x;
  if (i >= n4) return;
  float4 v = reinterpret_cast<const float4*>(in)[i];
  ushort4 o;
  o.x = f2bf(v.x); o.y = f2bf(v.y); o.z = f2bf(v.z); o.w = f2bf(v.w);
  reinterpret_cast<ushort4*>(out)[i] = o;
}

__global__ void k_bnfold(const float* __restrict__ g, const float* __restrict__ be,
                         const float* __restrict__ mu, const float* __restrict__ va,
                         float* __restrict__ A, float* __restrict__ B, int n) {
  int i = blockIdx.x * blockDim.x + threadIdx.x;
  if (i < n) {
    float a = g[i] * rsqrtf(va[i] + EPS_);
    A[i] = a;
    B[i] = be[i] - mu[i] * a;
  }
}

__global__ void k_biasexp(const float* __restrict__ biases, const int* __restrict__ idxs,
                          float* __restrict__ out) {
  int p = blockIdx.x * 256 + threadIdx.x;   // [0, 65536)
  int h = blockIdx.y;
  out[h * 65536 + p] = biases[h * 256 + idxs[p]];
}

// ---------------------------------------------------------------------------
// k_attn LDS map (dynamic, 106496 B):
//  XS  [256][32] bf16 (x tile)        @ 0       (16 KB)
//  WS  [128][32] bf16 (w tile)        @ 16384   (8 KB)
//  QK  [256][128] bf16 (q|k, BN'd)    @ 24576   (64 KB)   } same region,
//  VT  [128][256] bf16 (V^T half)     @ 24576   (64 KB)   } time-shared
//  P   8 waves x [32][32] bf16        @ 90112   (16 KB)
#define XS_OFF 0
#define WS_OFF 16384
#define QK_OFF 24576
#define VT_OFF 24576
#define P_OFF  90112
#define LDS_A  106496

__global__ __launch_bounds__(512, 2) void k_attn(
    const unsigned short* __restrict__ xg,    // bf16 [64*256][768]
    const unsigned short* __restrict__ wg,    // bf16 [4608][768]
    const float* __restrict__ bnA, const float* __restrict__ bnB,   // [4608]
    const float* __restrict__ biasx,          // [12][256][256] fp32
    unsigned short* __restrict__ og)          // bf16 [64*256][3072]
{
  extern __shared__ char smem[];
  const int tid = threadIdx.x;
  const int w  = tid >> 6;
  const int l  = tid & 63;
  const int lg = l >> 4;
  const int lr = l & 15;
  const int b  = blockIdx.x / HEADS;
  const int h  = blockIdx.x % HEADS;
  const unsigned short* xb = xg + (size_t)b * 256 * 768;
  const int wr = w >> 1, wc = w & 1;        // 4x2 wave grid for GEMM phases
  const int srow = tid >> 2, schk = tid & 3;
  const f32x4 fz = {0.f, 0.f, 0.f, 0.f};

  // ================= Phase 1: QK = BN(x @ Wqk^T) -> LDS =================
  f32x4 acc[4][4];
#pragma unroll
  for (int i = 0; i < 4; i++)
#pragma unroll
    for (int j = 0; j < 4; j++) acc[i][j] = fz;

  const unsigned short* wqk = wg + (size_t)h * 384 * 768;

  bf16x8 p0 = *reinterpret_cast<const bf16x8*>(xb + srow * 768 + schk * 8);
  bf16x8 p1 = *reinterpret_cast<const bf16x8*>(xb + (srow + 128) * 768 + schk * 8);
  bf16x8 pw = *reinterpret_cast<const bf16x8*>(wqk + srow * 768 + schk * 8);

#pragma unroll 1
  for (int k0 = 0; k0 < 768; k0 += 32) {
    *reinterpret_cast<bf16x8*>(smem + XS_OFF + SWZ(srow * 64 + schk * 16, srow)) = p0;
    *reinterpret_cast<bf16x8*>(smem + XS_OFF + SWZ((srow + 128) * 64 + schk * 16, srow + 128)) = p1;
    *reinterpret_cast<bf16x8*>(smem + WS_OFF + SWZ(srow * 64 + schk * 16, srow)) = pw;
    __syncthreads();
    int kn = (k0 + 32 < 768) ? k0 + 32 : 0;
    p0 = *reinterpret_cast<const bf16x8*>(xb + srow * 768 + kn + schk * 8);
    p1 = *reinterpret_cast<const bf16x8*>(xb + (srow + 128) * 768 + kn + schk * 8);
    pw = *reinterpret_cast<const bf16x8*>(wqk + srow * 768 + kn + schk * 8);
    bf16x8 af[4], bw[4];
#pragma unroll
    for (int i = 0; i < 4; i++) {
      int rn = wr * 64 + i * 16 + lr;
      af[i] = *reinterpret_cast<const bf16x8*>(smem + XS_OFF + SWZ(rn * 64 + lg * 16, rn));
    }
#pragma unroll
    for (int j = 0; j < 4; j++) {
      int rn = wc * 64 + j * 16 + lr;
      bw[j] = *reinterpret_cast<const bf16x8*>(smem + WS_OFF + SWZ(rn * 64 + lg * 16, rn));
    }
#pragma unroll
    for (int i = 0; i < 4; i++)
#pragma unroll
      for (int j = 0; j < 4; j++)
        acc[i][j] = mfma16(af[i], bw[j], acc[i][j]);
    __syncthreads();
  }

  // BN + store q|k (bf16) into QK LDS
#pragma unroll
  for (int j = 0; j < 4; j++) {
    int gcol = wc * 64 + j * 16 + lr;                 // 0..127 (q:0-63, k:64-127)
    float Af = bnA[h * 384 + gcol];
    float Bf = bnB[h * 384 + gcol];
#pragma unroll
    for (int i = 0; i < 4; i++) {
#pragma unroll
      for (int r = 0; r < 4; r++) {
        int n = wr * 64 + i * 16 + lg * 4 + r;
        float y = acc[i][j][r] * Af + Bf;
        *reinterpret_cast<unsigned short*>(smem + QK_OFF + SWZ(n * 256 + gcol * 2, n)) = f2bf(y);
      }
    }
  }
  __syncthreads();

  // ================= Phase 2: S = Q K^T, scale+bias, softmax =================
  // wave w owns q rows [w*32, w*32+32)
  f32x4 accS[2][16];
#pragma unroll
  for (int rt = 0; rt < 2; rt++)
#pragma unroll
    for (int kt = 0; kt < 16; kt++) accS[rt][kt] = fz;

  bf16x8 aq[2][2];
#pragma unroll
  for (int rt = 0; rt < 2; rt++)
#pragma unroll
    for (int ks = 0; ks < 2; ks++) {
      int n = w * 32 + rt * 16 + lr;
      aq[rt][ks] = *reinterpret_cast<const bf16x8*>(smem + QK_OFF + SWZ(n * 256 + ks * 64 + lg * 16, n));
    }
#pragma unroll
  for (int kt = 0; kt < 16; kt++) {
#pragma unroll
    for (int ks = 0; ks < 2; ks++) {
      int n = kt * 16 + lr;
      bf16x8 bk = *reinterpret_cast<const bf16x8*>(smem + QK_OFF + SWZ(n * 256 + 128 + ks * 64 + lg * 16, n));
      accS[0][kt] = mfma16(aq[0][ks], bk, accS[0][kt]);
      accS[1][kt] = mfma16(aq[1][ks], bk, accS[1][kt]);
    }
  }

  const float* bxp = biasx + h * 65536;
  float mx[2][4];
#pragma unroll
  for (int rt = 0; rt < 2; rt++)
#pragma unroll
    for (int r = 0; r < 4; r++) mx[rt][r] = -1e30f;

#pragma unroll
  for (int rt = 0; rt < 2; rt++) {
#pragma unroll
    for (int kt = 0; kt < 16; kt++) {
#pragma unroll
      for (int r = 0; r < 4; r++) {
        int q = w * 32 + rt * 16 + lg * 4 + r;
        int k = kt * 16 + lr;
        float s = accS[rt][kt][r] * SCALE_ + bxp[q * 256 + k];
        accS[rt][kt][r] = s;
        mx[rt][r] = fmaxf(mx[rt][r], s);
      }
    }
  }
  // row reduction: row lives in the 16 lanes sharing lg (xor 1,2,4,8 stay in-group)
#pragma unroll
  for (int rt = 0; rt < 2; rt++)
#pragma unroll
    for (int r = 0; r < 4; r++) {
      float m = mx[rt][r];
      m = fmaxf(m, __shfl_xor(m, 1));
      m = fmaxf(m, __shfl_xor(m, 2));
      m = fmaxf(m, __shfl_xor(m, 4));
      m = fmaxf(m, __shfl_xor(m, 8));
      mx[rt][r] = m;
    }

  float sm[2][4] = {{0.f,0.f,0.f,0.f},{0.f,0.f,0.f,0.f}};
  unsigned int pP[2][16][2];     // bf16-packed unnormalized probs (rows r0..r3)
#pragma unroll
  for (int rt = 0; rt < 2; rt++) {
#pragma unroll
    for (int kt = 0; kt < 16; kt++) {
      float e0 = __expf(accS[rt][kt][0] - mx[rt][0]);
      float e1 = __expf(accS[rt][kt][1] - mx[rt][1]);
      float e2 = __expf(accS[rt][kt][2] - mx[rt][2]);
      float e3 = __expf(accS[rt][kt][3] - mx[rt][3]);
      sm[rt][0] += e0; sm[rt][1] += e1; sm[rt][2] += e2; sm[rt][3] += e3;
      pP[rt][kt][0] = (unsigned)f2bf(e0) | ((unsigned)f2bf(e1) << 16);
      pP[rt][kt][1] = (unsigned)f2bf(e2) | ((unsigned)f2bf(e3) << 16);
    }
  }
  float rs[2][4];
#pragma unroll
  for (int rt = 0; rt < 2; rt++)
#pragma unroll
    for (int r = 0; r < 4; r++) {
      float s = sm[rt][r];
      s += __shfl_xor(s, 1);
      s += __shfl_xor(s, 2);
      s += __shfl_xor(s, 4);
      s += __shfl_xor(s, 8);
      rs[rt][r] = 1.f / s;
    }

  // ================= Phase 3+4: per d-half: V GEMM -> VT, then PV =================
  char* pbw = smem + P_OFF + w * 2048;       // wave-private [32][32] bf16
#pragma unroll 1
  for (int dh = 0; dh < 2; dh++) {
#pragma unroll
    for (int i = 0; i < 4; i++)
#pragma unroll
      for (int j = 0; j < 4; j++) acc[i][j] = fz;

    const unsigned short* wv = wg + ((size_t)h * 384 + 128 + dh * 128) * 768;
    p0 = *reinterpret_cast<const bf16x8*>(xb + srow * 768 + schk * 8);
    p1 = *reinterpret_cast<const bf16x8*>(xb + (srow + 128) * 768 + schk * 8);
    pw = *reinterpret_cast<const bf16x8*>(wv + srow * 768 + schk * 8);

#pragma unroll 1
    for (int k0 = 0; k0 < 768; k0 += 32) {
      *reinterpret_cast<bf16x8*>(smem + XS_OFF + SWZ(srow * 64 + schk * 16, srow)) = p0;
      *reinterpret_cast<bf16x8*>(smem + XS_OFF + SWZ((srow + 128) * 64 + schk * 16, srow + 128)) = p1;
      *reinterpret_cast<bf16x8*>(smem + WS_OFF + SWZ(srow * 64 + schk * 16, srow)) = pw;
      __syncthreads();
      int kn = (k0 + 32 < 768) ? k0 + 32 : 0;
      p0 = *reinterpret_cast<const bf16x8*>(xb + srow * 768 + kn + schk * 8);
      p1 = *reinterpret_cast<const bf16x8*>(xb + (srow + 128) * 768 + kn + schk * 8);
      pw = *reinterpret_cast<const bf16x8*>(wv + srow * 768 + kn + schk * 8);
      bf16x8 af[4], bw2[4];
#pragma unroll
      for (int i = 0; i < 4; i++) {
        int rn = wr * 64 + i * 16 + lr;
        af[i] = *reinterpret_cast<const bf16x8*>(smem + XS_OFF + SWZ(rn * 64 + lg * 16, rn));
      }
#pragma unroll
      for (int j = 0; j < 4; j++) {
        int rn = wc * 64 + j * 16 + lr;
        bw2[j] = *reinterpret_cast<const bf16x8*>(smem + WS_OFF + SWZ(rn * 64 + lg * 16, rn));
      }
#pragma unroll
      for (int i = 0; i < 4; i++)
#pragma unroll
        for (int j = 0; j < 4; j++)
          acc[i][j] = mfma16(af[i], bw2[j], acc[i][j]);
      __syncthreads();
    }

    // BN + TRANSPOSED store: VT[d][ktok], pairs of adjacent ktok packed as b32
#pragma unroll
    for (int j = 0; j < 4; j++) {
      int vcol = wc * 64 + j * 16 + lr;                // d within half, 0..127
      float Af = bnA[h * 384 + 128 + dh * 128 + vcol];
      float Bf = bnB[h * 384 + 128 + dh * 128 + vcol];
#pragma unroll
      for (int i = 0; i < 4; i++) {
        int nb = wr * 64 + i * 16 + lg * 4;            // k-token base (mult of 4)
        float y0 = acc[i][j][0] * Af + Bf;
        float y1 = acc[i][j][1] * Af + Bf;
        float y2 = acc[i][j][2] * Af + Bf;
        float y3 = acc[i][j][3] * Af + Bf;
        unsigned u0 = (unsigned)f2bf(y0) | ((unsigned)f2bf(y1) << 16);
        unsigned u1 = (unsigned)f2bf(y2) | ((unsigned)f2bf(y3) << 16);
        *reinterpret_cast<unsigned*>(smem + VT_OFF + SWZ(vcol * 512 + nb * 2, vcol)) = u0;
        *reinterpret_cast<unsigned*>(smem + VT_OFF + SWZ(vcol * 512 + nb * 2 + 4, vcol)) = u1;
      }
    }
    __syncthreads();

    // PV: out[32 q][128 d] per wave, k in 8 chunks of 32
    f32x4 accO[2][8];
#pragma unroll
    for (int rt = 0; rt < 2; rt++)
#pragma unroll
      for (int dt = 0; dt < 8; dt++) accO[rt][dt] = fz;

#pragma unroll
    for (int c = 0; c < 8; c++) {
      // stage this wave's P chunk (cols c*32..c*32+32) to wave-private LDS
#pragma unroll
      for (int rt = 0; rt < 2; rt++) {
#pragma unroll
        for (int t = 0; t < 2; t++) {
          int kt = c * 2 + t;
          int q0 = rt * 16 + lg * 4;
          int kc = t * 16 + lr;
          unsigned u0 = pP[rt][kt][0], u1 = pP[rt][kt][1];
          *reinterpret_cast<unsigned short*>(pbw + SWZ((q0 + 0) * 64 + kc * 2, q0 + 0)) = (unsigned short)(u0 & 0xffff);
          *reinterpret_cast<unsigned short*>(pbw + SWZ((q0 + 1) * 64 + kc * 2, q0 + 1)) = (unsigned short)(u0 >> 16);
          *reinterpret_cast<unsigned short*>(pbw + SWZ((q0 + 2) * 64 + kc * 2, q0 + 2)) = (unsigned short)(u1 & 0xffff);
          *reinterpret_cast<unsigned short*>(pbw + SWZ((q0 + 3) * 64 + kc * 2, q0 + 3)) = (unsigned short)(u1 >> 16);
        }
      }
      asm volatile("s_waitcnt lgkmcnt(0)" ::: "memory");
      bf16x8 pa[2];
#pragma unroll
      for (int rt = 0; rt < 2; rt++) {
        int rq = rt * 16 + lr;
        pa[rt] = *reinterpret_cast<const bf16x8*>(pbw + SWZ(rq * 64 + lg * 16, rq));
      }
#pragma unroll
      for (int dt = 0; dt < 8; dt++) {
        int d = dt * 16 + lr;
        bf16x8 bv = *reinterpret_cast<const bf16x8*>(smem + VT_OFF + SWZ(d * 512 + c * 64 + lg * 16, d));
        accO[0][dt] = mfma16(pa[0], bv, accO[0][dt]);
        accO[1][dt] = mfma16(pa[1], bv, accO[1][dt]);
      }
    }

    // epilogue: normalize, hardswish, store bf16
    unsigned short* ob = og + (size_t)b * 256 * 3072 + h * 256 + dh * 128;
#pragma unroll
    for (int rt = 0; rt < 2; rt++) {
#pragma unroll
      for (int dt = 0; dt < 8; dt++) {
#pragma unroll
        for (int r = 0; r < 4; r++) {
          int q = w * 32 + rt * 16 + lg * 4 + r;
          int d = dt * 16 + lr;
          float o = accO[rt][dt][r] * rs[rt][r];
          float hsw = fminf(fmaxf(o + 3.f, 0.f), 6.f);
          o = o * hsw * (1.f / 6.f);
          ob[(size_t)q * 3072 + d] = f2bf(o);
        }
      }
    }
    __syncthreads();
  }
}

// ---------------------------------------------------------------------------
// k_proj: out[16384][768] = BN(attnout @ proj_w^T), bf16 MFMA, 128x128 tile
#define PX_OFF 0
#define PW_OFF 8192

__global__ __launch_bounds__(256, 2) void k_proj(
    const unsigned short* __restrict__ ag,    // bf16 [16384][3072]
    const unsigned short* __restrict__ wg,    // bf16 [768][3072]
    const float* __restrict__ bnA, const float* __restrict__ bnB,   // [768]
    float* __restrict__ out)                  // fp32 [16384][768]
{
  __shared__ char smem[16384];
  const int tid = threadIdx.x;
  const int w  = tid >> 6, l = tid & 63, lg = l >> 4, lr = l & 15;
  const int wr = w >> 1, wc = w & 1;
  const int bm = blockIdx.x % 128, bn = blockIdx.x / 128;
  const int srow = tid >> 2, schk = tid & 3;
  const f32x4 fz = {0.f, 0.f, 0.f, 0.f};

  const unsigned short* arow = ag + (size_t)bm * 128 * 3072;
  const unsigned short* wrow = wg + (size_t)bn * 128 * 3072;

  f32x4 acc[4][4];
#pragma unroll
  for (int i = 0; i < 4; i++)
#pragma unroll
    for (int j = 0; j < 4; j++) acc[i][j] = fz;

  bf16x8 a0 = *reinterpret_cast<const bf16x8*>(arow + srow * 3072 + schk * 8);
  bf16x8 a1 = *reinterpret_cast<const bf16x8*>(arow + (srow + 64) * 3072 + schk * 8);
  bf16x8 b0 = *reinterpret_cast<const bf16x8*>(wrow + srow * 3072 + schk * 8);
  bf16x8 b1 = *reinterpret_cast<const bf16x8*>(wrow + (srow + 64) * 3072 + schk * 8);

#pragma unroll 1
  for (int k0 = 0; k0 < 3072; k0 += 32) {
    *reinterpret_cast<bf16x8*>(smem + PX_OFF + SWZ(srow * 64 + schk * 16, srow)) = a0;
    *reinterpret_cast<bf16x8*>(smem + PX_OFF + SWZ((srow + 64) * 64 + schk * 16, srow + 64)) = a1;
    *reinterpret_cast<bf16x8*>(smem + PW_OFF + SWZ(srow * 64 + schk * 16, srow)) = b0;
    *reinterpret_cast<bf16x8*>(smem + PW_OFF + SWZ((srow + 64) * 64 + schk * 16, srow + 64)) = b1;
    __syncthreads();
    int kn = (k0 + 32 < 3072) ? k0 + 32 : 0;
    a0 = *reinterpret_cast<const bf16x8*>(arow + srow * 3072 + kn + schk * 8);
    a1 = *reinterpret_cast<const bf16x8*>(arow + (srow + 64) * 3072 + kn + schk * 8);
    b0 = *reinterpret_cast<const bf16x8*>(wrow + srow * 3072 + kn + schk * 8);
    b1 = *reinterpret_cast<const bf16x8*>(wrow + (srow + 64) * 3072 + kn + schk * 8);
    bf16x8 af[4], bf_[4];
#pragma unroll
    for (int i = 0; i < 4; i++) {
      int rn = wr * 64 + i * 16 + lr;
      af[i] = *reinterpret_cast<const bf16x8*>(smem + PX_OFF + SWZ(rn * 64 + lg * 16, rn));
    }
#pragma unroll
    for (int j = 0; j < 4; j++) {
      int rn = wc * 64 + j * 16 + lr;
      bf_[j] = *reinterpret_cast<const bf16x8*>(smem + PW_OFF + SWZ(rn * 64 + lg * 16, rn));
    }
#pragma unroll
    for (int i = 0; i < 4; i++)
#pragma unroll
      for (int j = 0; j < 4; j++)
        acc[i][j] = mfma16(af[i], bf_[j], acc[i][j]);
    __syncthreads();
  }

#pragma unroll
  for (int j = 0; j < 4; j++) {
    int c = bn * 128 + wc * 64 + j * 16 + lr;
    float Af = bnA[c], Bf = bnB[c];
#pragma unroll
    for (int i = 0; i < 4; i++) {
#pragma unroll
      for (int r = 0; r < 4; r++) {
        int m = bm * 128 + wr * 64 + i * 16 + lg * 4 + r;
        out[(size_t)m * 768 + c] = acc[i][j][r] * Af + Bf;
      }
    }
  }
}

// ---------------------------------------------------------------------------
extern "C" void kernel_launch(void* const* d_in, const int* in_sizes, int n_in,
                              void* d_out, int out_size, void* d_ws, size_t ws_size,
                              hipStream_t stream) {
  const float* x      = (const float*)d_in[0];
  const float* qkv_w  = (const float*)d_in[1];
  const float* qg     = (const float*)d_in[2];
  const float* qb     = (const float*)d_in[3];
  const float* qm     = (const float*)d_in[4];
  const float* qv     = (const float*)d_in[5];
  const float* biases = (const float*)d_in[6];
  const float* proj_w = (const float*)d_in[7];
  const float* pg     = (const float*)d_in[8];
  const float* pbe    = (const float*)d_in[9];
  const float* pm     = (const float*)d_in[10];
  const float* pv     = (const float*)d_in[11];
  const int*   bidx   = (const int*)d_in[12];

  char* ws = (char*)d_ws;
  unsigned short* x_bf  = (unsigned short*)(ws);               // 25,165,824 B
  unsigned short* wq_bf = (unsigned short*)(ws + 25165824);    //  7,077,888 B
  unsigned short* wp_bf = (unsigned short*)(ws + 32243712);    //  4,718,592 B
  float* bnAq  = (float*)(ws + 36962304);                      //     18,432 B
  float* bnBq  = (float*)(ws + 36980736);                      //     18,432 B
  float* bnAp  = (float*)(ws + 36999168);                      //      3,072 B
  float* bnBp  = (float*)(ws + 37002240);                      //      3,072 B
  float* biasx = (float*)(ws + 37005312);                      //  3,145,728 B
  unsigned short* attno = (unsigned short*)(ws + 40151040);    // 100,663,296 B -> 140,814,336 total

  (void)in_sizes; (void)n_in; (void)out_size; (void)ws_size;

  (void)hipFuncSetAttribute((const void*)k_attn,
                            hipFuncAttributeMaxDynamicSharedMemorySize, LDS_A);

  k_cvt<<<dim3((3145728 + 255) / 256), dim3(256), 0, stream>>>(x, x_bf, 3145728);
  k_cvt<<<dim3((884736 + 255) / 256), dim3(256), 0, stream>>>(qkv_w, wq_bf, 884736);
  k_cvt<<<dim3((589824 + 255) / 256), dim3(256), 0, stream>>>(proj_w, wp_bf, 589824);
  k_bnfold<<<dim3(18), dim3(256), 0, stream>>>(qg, qb, qm, qv, bnAq, bnBq, 4608);
  k_bnfold<<<dim3(3), dim3(256), 0, stream>>>(pg, pbe, pm, pv, bnAp, bnBp, 768);
  k_biasexp<<<dim3(256, 12), dim3(256), 0, stream>>>(biases, bidx, biasx);
  k_attn<<<dim3(768), dim3(512), LDS_A, stream>>>(x_bf, wq_bf, bnAq, bnBq, biasx, attno);
  k_proj<<<dim3(768), dim3(256), 0, stream>>>(attno, wp_bf, bnAp, bnBp, (float*)d_out);
}

// Round 2
// 709.403 us; speedup vs baseline: 1.0310x; 1.0310x over previous
//
#include <hip/hip_runtime.h>
#include <hip/hip_bf16.h>
#include <stdint.h>

// ---------------------------------------------------------------------------
// LeViT attention block, split pipeline (round 1):
//  k_cvt      : fp32 -> bf16 (x, qkv_w, proj_w)
//  k_bnfold   : fold BN into per-channel A,B  (y = x*A + B)
//  k_biasexp  : expand attn_biases[h, bias_idxs] -> [12][256][256] fp32
//  k_qkv      : m97-style GEMM (M=CB*512? no: M=CB*256? M-tiles x 36) ->
//               BN -> Q[bh][tok][64], K[bh][tok][64], VT[bh][d][tok] bf16
//  k_attn2    : per (b,h,q-half): QK^T + bias + softmax + PV + hardswish
//  k_proj     : m97-style GEMM (K=3072) + BN -> d_out fp32
// MFMA 16x16x32 bf16, C/D layout col=lane&15, row=(lane>>4)*4+reg (m89).
// LDS XOR swizzle: byte ^= (row&7)<<4; global_load_lds uses the inverse
// swizzle on the per-lane GLOBAL source (LDS dest linear) per guide §5/m173.
// ---------------------------------------------------------------------------

typedef __attribute__((ext_vector_type(8))) __bf16 bf16x8;
typedef __attribute__((ext_vector_type(4))) float  f32x4;
typedef unsigned int u32;
typedef unsigned short u16;

#define EPS_   1e-5f
#define SCALE_ 0.125f

#define SWZ(byte, row) ((byte) ^ (((row) & 7) << 4))

__device__ __forceinline__ u16 f2bf(float x) {
  __hip_bfloat16 h = __float2bfloat16(x);
  return *reinterpret_cast<u16*>(&h);
}
__device__ __forceinline__ f32x4 mfma16(bf16x8 a, bf16x8 b, f32x4 c) {
  return __builtin_amdgcn_mfma_f32_16x16x32_bf16(a, b, c, 0, 0, 0);
}
__device__ __forceinline__ void gll16(const void* g, void* l) {
  __builtin_amdgcn_global_load_lds((const __attribute__((address_space(1))) u32*)g,
                                   (__attribute__((address_space(3))) u32*)l, 16, 0, 0);
}

// ---------------------------------------------------------------------------
__global__ void k_cvt(const float* __restrict__ in, u16* __restrict__ out, int n4) {
  int i = blockIdx.x * blockDim.x + threadIdx.x;
  if (i >= n4) return;
  float4 v = reinterpret_cast<const float4*>(in)[i];
  ushort4 o;
  o.x = f2bf(v.x); o.y = f2bf(v.y); o.z = f2bf(v.z); o.w = f2bf(v.w);
  reinterpret_cast<ushort4*>(out)[i] = o;
}

__global__ void k_bnfold(const float* __restrict__ g, const float* __restrict__ be,
                         const float* __restrict__ mu, const float* __restrict__ va,
                         float* __restrict__ A, float* __restrict__ B, int n) {
  int i = blockIdx.x * blockDim.x + threadIdx.x;
  if (i < n) {
    float a = g[i] * rsqrtf(va[i] + EPS_);
    A[i] = a;
    B[i] = be[i] - mu[i] * a;
  }
}

__global__ void k_biasexp(const float* __restrict__ biases, const int* __restrict__ idxs,
                          float* __restrict__ out) {
  int p = blockIdx.x * 256 + threadIdx.x;
  int h = blockIdx.y;
  out[h * 65536 + p] = biases[h * 256 + idxs[p]];
}

// ---------------------------------------------------------------------------
// k_qkv: C[m, n] = BN(x[m, :768] . W[n, :768]) for n in [bn*128, bn*128+128),
// tile 128x128, BK=32 double-buffered via global_load_lds(16B).
// n-tile mapping: 384 cols/head = 3 tiles -> h = bn/3, sub = bn%3
//   sub 0: cols 0-63 = Q, 64-127 = K  (straight [tok][c] store via LDS)
//   sub 1/2: V d-channels -> VT[d][tok] (transposed store via LDS)
__global__ __launch_bounds__(256, 4) void k_qkv(
    const u16* __restrict__ xg,       // [CB*256][768] (chunk base)
    const u16* __restrict__ wg,       // [4608][768]
    const float* __restrict__ bnA, const float* __restrict__ bnB,
    u16* __restrict__ qb,             // [CB*12][256][64]
    u16* __restrict__ kb,             // [CB*12][256][64]
    u16* __restrict__ vt)             // [CB*12][256][256]
{
  __shared__ char smem[32768];
  const int tid = threadIdx.x;
  const int w = tid >> 6, l = tid & 63, lg = l >> 4, lr = l & 15;
  const int wr = w >> 1, wc = w & 1;

  int bid = blockIdx.x;
  bid = (bid & 7) * ((int)gridDim.x >> 3) + (bid >> 3);   // XCD swizzle (nwg%8==0)
  const int bm = bid / 36, bn = bid % 36;

  const u16* Ab = xg + (size_t)bm * 128 * 768;
  const u16* Bb = wg + (size_t)bn * 128 * 768;

  // inverse-swizzle source mapping for the 2 staging issues per thread
  int ro[2], co[2];
#pragma unroll
  for (int j = 0; j < 2; j++) {
    int p = (j * 4 + w) * 1024 + l * 16;     // linear phys offset in 8KB tile
    int rhi = p >> 7;
    int r0  = ((p >> 6) ^ (p >> 8)) & 1;
    int row = (rhi << 1) | r0;
    int g0  = ((p >> 4) & 1) ^ r0;
    int g1  = ((p >> 5) ^ (p >> 7)) & 1;
    ro[j] = row;
    co[j] = (g0 | (g1 << 1)) * 8;
  }

  const f32x4 fz = {0.f, 0.f, 0.f, 0.f};
  f32x4 acc[4][4];
#pragma unroll
  for (int i = 0; i < 4; i++)
#pragma unroll
    for (int j = 0; j < 4; j++) acc[i][j] = fz;

  // prologue stage into buf0
#pragma unroll
  for (int j = 0; j < 2; j++) {
    gll16(Ab + ro[j] * 768 + co[j], smem + (j * 4 + w) * 1024);
    gll16(Bb + ro[j] * 768 + co[j], smem + 8192 + (j * 4 + w) * 1024);
  }
  __syncthreads();

#pragma unroll 1
  for (int t = 0; t < 24; t++) {
    const int cur = (t & 1) * 16384;
    if (t + 1 < 24) {
      const int nxt = ((t + 1) & 1) * 16384;
      const int k0 = (t + 1) * 32;
#pragma unroll
      for (int j = 0; j < 2; j++) {
        gll16(Ab + ro[j] * 768 + k0 + co[j], smem + nxt + (j * 4 + w) * 1024);
        gll16(Bb + ro[j] * 768 + k0 + co[j], smem + nxt + 8192 + (j * 4 + w) * 1024);
      }
    }
    bf16x8 af[4], bw[4];
#pragma unroll
    for (int i = 0; i < 4; i++) {
      int rn = wr * 64 + i * 16 + lr;
      af[i] = *reinterpret_cast<const bf16x8*>(smem + cur + SWZ(rn * 64 + lg * 16, rn));
    }
#pragma unroll
    for (int j = 0; j < 4; j++) {
      int rn = wc * 64 + j * 16 + lr;
      bw[j] = *reinterpret_cast<const bf16x8*>(smem + cur + 8192 + SWZ(rn * 64 + lg * 16, rn));
    }
#pragma unroll
    for (int i = 0; i < 4; i++)
#pragma unroll
      for (int j = 0; j < 4; j++)
        acc[i][j] = mfma16(af[i], bw[j], acc[i][j]);
    __syncthreads();
  }

  // -------- epilogue: BN + bf16 + layout via LDS (reuse staging region) ----
  const int h = bn / 3, sub = bn - h * 3;
  const int bL = bm >> 1;                 // chunk-local batch
  const int bhL = bL * 12 + h;

  if (sub == 0) {
    // straight tile [tok128][col128] bf16 (rows 256B)
#pragma unroll
    for (int j = 0; j < 4; j++) {
      int col = wc * 64 + j * 16 + lr;
      float Af = bnA[bn * 128 + col], Bf = bnB[bn * 128 + col];
#pragma unroll
      for (int i = 0; i < 4; i++) {
#pragma unroll
        for (int r = 0; r < 4; r++) {
          int tok = wr * 64 + i * 16 + lg * 4 + r;
          *reinterpret_cast<u16*>(smem + SWZ(tok * 256 + col * 2, tok)) =
              f2bf(acc[i][j][r] * Af + Bf);
        }
      }
    }
    __syncthreads();
    int row = tid >> 1, half = tid & 1;
    int tokg = (bm & 1) * 128 + row;
    u16* dst = (half ? kb : qb) + (size_t)bhL * 16384 + (size_t)tokg * 64;
#pragma unroll
    for (int e = 0; e < 8; e++) {
      bf16x8 v = *reinterpret_cast<const bf16x8*>(smem + SWZ(row * 256 + half * 128 + e * 16, row));
      *reinterpret_cast<bf16x8*>(dst + e * 8) = v;
    }
  } else {
    // transposed tile [d'128][tok128] bf16
#pragma unroll
    for (int j = 0; j < 4; j++) {
      int dl = wc * 64 + j * 16 + lr;
      float Af = bnA[bn * 128 + dl], Bf = bnB[bn * 128 + dl];
#pragma unroll
      for (int i = 0; i < 4; i++) {
        int tok = wr * 64 + i * 16 + lg * 4;
        float y0 = acc[i][j][0] * Af + Bf;
        float y1 = acc[i][j][1] * Af + Bf;
        float y2 = acc[i][j][2] * Af + Bf;
        float y3 = acc[i][j][3] * Af + Bf;
        u32 u0 = (u32)f2bf(y0) | ((u32)f2bf(y1) << 16);
        u32 u1 = (u32)f2bf(y2) | ((u32)f2bf(y3) << 16);
        *reinterpret_cast<u32*>(smem + SWZ(dl * 256 + tok * 2, dl)) = u0;
        *reinterpret_cast<u32*>(smem + SWZ(dl * 256 + tok * 2 + 4, dl)) = u1;
      }
    }
    __syncthreads();
    int dl = tid >> 1, half = tid & 1;
    int d = (sub - 1) * 128 + dl;
    u16* dst = vt + (size_t)bhL * 65536 + (size_t)d * 256 + (bm & 1) * 128 + half * 64;
#pragma unroll
    for (int e = 0; e < 8; e++) {
      bf16x8 v = *reinterpret_cast<const bf16x8*>(smem + SWZ(dl * 256 + half * 128 + e * 16, dl));
      *reinterpret_cast<bf16x8*>(dst + e * 8) = v;
    }
  }
}

// ---------------------------------------------------------------------------
// k_attn2: block = (bhL, q-half), 4 waves x 32 q-rows = 128 q rows.
// K in swizzled LDS (32KB); Q direct global->regs; VT streamed from global.
#define KS_OFF 0
#define PB_OFF 32768
__global__ __launch_bounds__(256, 2) void k_attn2(
    const u16* __restrict__ qb, const u16* __restrict__ kb,
    const u16* __restrict__ vt, const float* __restrict__ biasx,
    u16* __restrict__ og)             // [CB*256][3072]
{
  __shared__ char smem[40960];
  const int tid = threadIdx.x;
  const int w = tid >> 6, l = tid & 63, lg = l >> 4, lr = l & 15;
  const int bhL = blockIdx.x >> 1, qh = blockIdx.x & 1;
  const int h = bhL % 12, bL = bhL / 12;
  const int qbase = qh * 128 + w * 32;
  const f32x4 fz = {0.f, 0.f, 0.f, 0.f};

  // K -> LDS (swizzled [256][64] bf16, rows 128B)
  const u16* kp = kb + (size_t)bhL * 16384;
#pragma unroll
  for (int s = 0; s < 8; s++) {
    int slot = s * 256 + tid;
    int row = slot >> 3, ch = slot & 7;
    bf16x8 kv = *reinterpret_cast<const bf16x8*>(kp + row * 64 + ch * 8);
    *reinterpret_cast<bf16x8*>(smem + KS_OFF + SWZ(row * 128 + ch * 16, row)) = kv;
  }
  // Q frags direct from global
  const u16* qp = qb + (size_t)bhL * 16384;
  bf16x8 aq[2][2];
#pragma unroll
  for (int rt = 0; rt < 2; rt++)
#pragma unroll
    for (int ks = 0; ks < 2; ks++)
      aq[rt][ks] = *reinterpret_cast<const bf16x8*>(qp + (qbase + rt * 16 + lr) * 64 + ks * 32 + lg * 8);
  __syncthreads();

  const float* bxp = biasx + h * 65536;
  u32 pP[2][16][2];
  float rs[2][4];
#pragma unroll
  for (int rt = 0; rt < 2; rt++) {
    f32x4 accS[16];
#pragma unroll
    for (int kt = 0; kt < 16; kt++) accS[kt] = fz;
#pragma unroll
    for (int kt = 0; kt < 16; kt++) {
#pragma unroll
      for (int ks = 0; ks < 2; ks++) {
        int n = kt * 16 + lr;
        bf16x8 bk = *reinterpret_cast<const bf16x8*>(smem + KS_OFF + SWZ(n * 128 + (ks * 4 + lg) * 16, n));
        accS[kt] = mfma16(aq[rt][ks], bk, accS[kt]);
      }
    }
    float mx[4] = {-1e30f, -1e30f, -1e30f, -1e30f};
#pragma unroll
    for (int kt = 0; kt < 16; kt++) {
#pragma unroll
      for (int r = 0; r < 4; r++) {
        int q = qbase + rt * 16 + lg * 4 + r;
        float s = accS[kt][r] * SCALE_ + bxp[q * 256 + kt * 16 + lr];
        accS[kt][r] = s;
        mx[r] = fmaxf(mx[r], s);
      }
    }
#pragma unroll
    for (int r = 0; r < 4; r++) {
      float m = mx[r];
      m = fmaxf(m, __shfl_xor(m, 1));
      m = fmaxf(m, __shfl_xor(m, 2));
      m = fmaxf(m, __shfl_xor(m, 4));
      m = fmaxf(m, __shfl_xor(m, 8));
      mx[r] = m;
    }
    float sm[4] = {0.f, 0.f, 0.f, 0.f};
#pragma unroll
    for (int kt = 0; kt < 16; kt++) {
      float e0 = __expf(accS[kt][0] - mx[0]);
      float e1 = __expf(accS[kt][1] - mx[1]);
      float e2 = __expf(accS[kt][2] - mx[2]);
      float e3 = __expf(accS[kt][3] - mx[3]);
      sm[0] += e0; sm[1] += e1; sm[2] += e2; sm[3] += e3;
      pP[rt][kt][0] = (u32)f2bf(e0) | ((u32)f2bf(e1) << 16);
      pP[rt][kt][1] = (u32)f2bf(e2) | ((u32)f2bf(e3) << 16);
    }
#pragma unroll
    for (int r = 0; r < 4; r++) {
      float s = sm[r];
      s += __shfl_xor(s, 1);
      s += __shfl_xor(s, 2);
      s += __shfl_xor(s, 4);
      s += __shfl_xor(s, 8);
      rs[rt][r] = 1.f / s;
    }
  }

  // PV per d-half: P staged in wave-private LDS, VT streamed from global
  const u16* vp = vt + (size_t)bhL * 65536;
  char* pbw = smem + PB_OFF + w * 2048;
  u16* ob = og + (size_t)bL * 256 * 3072 + h * 256;
#pragma unroll 1
  for (int dh = 0; dh < 2; dh++) {
    f32x4 accO[2][8];
#pragma unroll
    for (int rt = 0; rt < 2; rt++)
#pragma unroll
      for (int dt = 0; dt < 8; dt++) accO[rt][dt] = fz;

#pragma unroll
    for (int c = 0; c < 8; c++) {
#pragma unroll
      for (int rt = 0; rt < 2; rt++) {
#pragma unroll
        for (int t = 0; t < 2; t++) {
          int kt = c * 2 + t;
          int q0 = rt * 16 + lg * 4;
          int kc = t * 16 + lr;
          u32 u0 = pP[rt][kt][0], u1 = pP[rt][kt][1];
          *reinterpret_cast<u16*>(pbw + SWZ((q0 + 0) * 64 + kc * 2, q0 + 0)) = (u16)(u0 & 0xffff);
          *reinterpret_cast<u16*>(pbw + SWZ((q0 + 1) * 64 + kc * 2, q0 + 1)) = (u16)(u0 >> 16);
          *reinterpret_cast<u16*>(pbw + SWZ((q0 + 2) * 64 + kc * 2, q0 + 2)) = (u16)(u1 & 0xffff);
          *reinterpret_cast<u16*>(pbw + SWZ((q0 + 3) * 64 + kc * 2, q0 + 3)) = (u16)(u1 >> 16);
        }
      }
      asm volatile("s_waitcnt lgkmcnt(0)" ::: "memory");
      bf16x8 pa[2];
#pragma unroll
      for (int rt = 0; rt < 2; rt++) {
        int rq = rt * 16 + lr;
        pa[rt] = *reinterpret_cast<const bf16x8*>(pbw + SWZ(rq * 64 + lg * 16, rq));
      }
#pragma unroll
      for (int dt = 0; dt < 8; dt++) {
        bf16x8 bv = *reinterpret_cast<const bf16x8*>(vp + (size_t)(dh * 128 + dt * 16 + lr) * 256 + c * 32 + lg * 8);
        accO[0][dt] = mfma16(pa[0], bv, accO[0][dt]);
        accO[1][dt] = mfma16(pa[1], bv, accO[1][dt]);
      }
    }
    // normalize + hardswish + store
#pragma unroll
    for (int rt = 0; rt < 2; rt++) {
#pragma unroll
      for (int dt = 0; dt < 8; dt++) {
#pragma unroll
        for (int r = 0; r < 4; r++) {
          int q = qbase + rt * 16 + lg * 4 + r;
          int d = dh * 128 + dt * 16 + lr;
          float o = accO[rt][dt][r] * rs[rt][r];
          float hsw = fminf(fmaxf(o + 3.f, 0.f), 6.f);
          o = o * hsw * (1.f / 6.f);
          ob[(size_t)q * 3072 + d] = f2bf(o);
        }
      }
    }
  }
}

// ---------------------------------------------------------------------------
// k_proj: out[m][c] = BN(attno[m,:3072] . proj_w[c,:3072]); same m97 template.
__global__ __launch_bounds__(256, 4) void k_proj(
    const u16* __restrict__ ag,       // [CB*256][3072]
    const u16* __restrict__ wg,       // [768][3072]
    const float* __restrict__ bnA, const float* __restrict__ bnB,
    float* __restrict__ out)          // [CB*256][768] (chunk base)
{
  __shared__ char smem[32768];
  const int tid = threadIdx.x;
  const int w = tid >> 6, l = tid & 63, lg = l >> 4, lr = l & 15;
  const int wr = w >> 1, wc = w & 1;

  int bid = blockIdx.x;
  bid = (bid & 7) * ((int)gridDim.x >> 3) + (bid >> 3);
  const int bm = bid / 6, bn = bid % 6;

  const u16* Ab = ag + (size_t)bm * 128 * 3072;
  const u16* Bb = wg + (size_t)bn * 128 * 3072;

  int ro[2], co[2];
#pragma unroll
  for (int j = 0; j < 2; j++) {
    int p = (j * 4 + w) * 1024 + l * 16;
    int rhi = p >> 7;
    int r0  = ((p >> 6) ^ (p >> 8)) & 1;
    int row = (rhi << 1) | r0;
    int g0  = ((p >> 4) & 1) ^ r0;
    int g1  = ((p >> 5) ^ (p >> 7)) & 1;
    ro[j] = row;
    co[j] = (g0 | (g1 << 1)) * 8;
  }

  const f32x4 fz = {0.f, 0.f, 0.f, 0.f};
  f32x4 acc[4][4];
#pragma unroll
  for (int i = 0; i < 4; i++)
#pragma unroll
    for (int j = 0; j < 4; j++) acc[i][j] = fz;

#pragma unroll
  for (int j = 0; j < 2; j++) {
    gll16(Ab + ro[j] * 3072 + co[j], smem + (j * 4 + w) * 1024);
    gll16(Bb + ro[j] * 3072 + co[j], smem + 8192 + (j * 4 + w) * 1024);
  }
  __syncthreads();

#pragma unroll 1
  for (int t = 0; t < 96; t++) {
    const int cur = (t & 1) * 16384;
    if (t + 1 < 96) {
      const int nxt = ((t + 1) & 1) * 16384;
      const int k0 = (t + 1) * 32;
#pragma unroll
      for (int j = 0; j < 2; j++) {
        gll16(Ab + ro[j] * 3072 + k0 + co[j], smem + nxt + (j * 4 + w) * 1024);
        gll16(Bb + ro[j] * 3072 + k0 + co[j], smem + nxt + 8192 + (j * 4 + w) * 1024);
      }
    }
    bf16x8 af[4], bw[4];
#pragma unroll
    for (int i = 0; i < 4; i++) {
      int rn = wr * 64 + i * 16 + lr;
      af[i] = *reinterpret_cast<const bf16x8*>(smem + cur + SWZ(rn * 64 + lg * 16, rn));
    }
#pragma unroll
    for (int j = 0; j < 4; j++) {
      int rn = wc * 64 + j * 16 + lr;
      bw[j] = *reinterpret_cast<const bf16x8*>(smem + cur + 8192 + SWZ(rn * 64 + lg * 16, rn));
    }
#pragma unroll
    for (int i = 0; i < 4; i++)
#pragma unroll
      for (int j = 0; j < 4; j++)
        acc[i][j] = mfma16(af[i], bw[j], acc[i][j]);
    __syncthreads();
  }

#pragma unroll
  for (int j = 0; j < 4; j++) {
    int c = bn * 128 + wc * 64 + j * 16 + lr;
    float Af = bnA[c], Bf = bnB[c];
#pragma unroll
    for (int i = 0; i < 4; i++) {
#pragma unroll
      for (int r = 0; r < 4; r++) {
        int m = bm * 128 + wr * 64 + i * 16 + lg * 4 + r;
        out[(size_t)m * 768 + c] = acc[i][j][r] * Af + Bf;
      }
    }
  }
}

// ---------------------------------------------------------------------------
extern "C" void kernel_launch(void* const* d_in, const int* in_sizes, int n_in,
                              void* d_out, int out_size, void* d_ws, size_t ws_size,
                              hipStream_t stream) {
  const float* x      = (const float*)d_in[0];
  const float* qkv_w  = (const float*)d_in[1];
  const float* qg     = (const float*)d_in[2];
  const float* qbe    = (const float*)d_in[3];
  const float* qm     = (const float*)d_in[4];
  const float* qv     = (const float*)d_in[5];
  const float* biases = (const float*)d_in[6];
  const float* proj_w = (const float*)d_in[7];
  const float* pg     = (const float*)d_in[8];
  const float* pbe    = (const float*)d_in[9];
  const float* pm     = (const float*)d_in[10];
  const float* pv     = (const float*)d_in[11];
  const int*   bidx   = (const int*)d_in[12];
  (void)in_sizes; (void)n_in; (void)out_size;

  char* ws = (char*)d_ws;
  u16*   x_bf  = (u16*)(ws);                       // 25,165,824
  u16*   wq_bf = (u16*)(ws + 25165824);            //  7,077,888
  u16*   wp_bf = (u16*)(ws + 32243712);            //  4,718,592
  float* bnAq  = (float*)(ws + 36962304);
  float* bnBq  = (float*)(ws + 36980736);
  float* bnAp  = (float*)(ws + 36999168);
  float* bnBp  = (float*)(ws + 37002240);
  float* biasx = (float*)(ws + 37005312);          //  3,145,728
  char*  cbuf  = ws + 40151040;                    // chunked region

  const size_t FIXED = 40151040, PERB = 3932160;
  int CB = 16;
  if (ws_size >= FIXED + 64 * PERB) CB = 64;
  else if (ws_size >= FIXED + 32 * PERB) CB = 32;

  size_t qsz = (size_t)CB * 393216;      // Q bf16 bytes per chunk
  size_t vsz = (size_t)CB * 1572864;     // VT / attno bytes per chunk
  u16* qbuf = (u16*)(cbuf);
  u16* kbuf = (u16*)(cbuf + qsz);
  u16* vbuf = (u16*)(cbuf + 2 * qsz);
  u16* abuf = (u16*)(cbuf + 2 * qsz + vsz);

  k_cvt<<<dim3(12288), dim3(256), 0, stream>>>(x, x_bf, 3145728);
  k_cvt<<<dim3(3456),  dim3(256), 0, stream>>>(qkv_w, wq_bf, 884736);
  k_cvt<<<dim3(2304),  dim3(256), 0, stream>>>(proj_w, wp_bf, 589824);
  k_bnfold<<<dim3(18), dim3(256), 0, stream>>>(qg, qbe, qm, qv, bnAq, bnBq, 4608);
  k_bnfold<<<dim3(3),  dim3(256), 0, stream>>>(pg, pbe, pm, pv, bnAp, bnBp, 768);
  k_biasexp<<<dim3(256, 12), dim3(256), 0, stream>>>(biases, bidx, biasx);

  for (int b0 = 0; b0 < 64; b0 += CB) {
    const u16* xc = x_bf + (size_t)b0 * 256 * 768;
    float* oc = (float*)d_out + (size_t)b0 * 256 * 768;
    k_qkv<<<dim3(CB * 72), dim3(256), 0, stream>>>(xc, wq_bf, bnAq, bnBq, qbuf, kbuf, vbuf);
    k_attn2<<<dim3(CB * 24), dim3(256), 0, stream>>>(qbuf, kbuf, vbuf, biasx, abuf);
    k_proj<<<dim3(CB * 12), dim3(256), 0, stream>>>(abuf, wp_bf, bnAp, bnBp, oc);
  }
}